// Round 2
// baseline (587.003 us; speedup 1.0000x reference)
//
#include <hip/hip_runtime.h>
#include <math.h>

// DCT2net fused kernel, R2.
//   t[ki,kj]  = sum_{x,y} c1[x][ki] c1[y][kj] X[h0+x, w0+y]   (separable DCT)
//   nz = shrink(t/(3s));  w = 1/(1+sum nz);  yw = w * t * nz
//   z[dx,dy]  = sum_{ki,kj} c1[dx][ki] c1[dy][kj] yw           (inverse = same c1)
//   out[a,b]  = fold(z) / boxsum13(w),  output row a needs patch rows a..a+12
//
// R2 changes vs R1:
//  - Rring (43 KB LDS) -> 13-register shift ring Rv (the vertical DCT at (j,lane)
//    consumes exactly this thread's last 13 horizontal-DCT outputs). -1 barrier,
//    -13 ds_read/step, LDS 50.7 KB -> 14.2 KB.
//  - ju = readfirstlane(tid>>6): all c1 accesses become scalar (SGPR operands),
//    wave-uniform branches become s_cbranch.
//  - Hwreg register ring -> LDS wring[13][64] (w box-sum read only by wave 0 at flush).
//  - inverse vertical DCT uses DCT even/odd symmetry: 169 -> ~123 VALU ops.
//  - input row prefetch (global load issued at top, consumed next iteration).
//  - grid 240 -> 500 blocks (25 row segments of 20), __launch_bounds__(832,7)
//    caps VGPR at 73 so two 13-wave blocks (26 waves) fit per CU.

#define P13   13
#define IMGW  512
#define OUTW  488
#define WC    52            // output cols per block
#define PWN   64            // patch cols per block = one wave
#define NJ    13            // kj waves
#define SEGH  20            // output rows per block
#define NSEG  25            // 25*20 = 500 >= 488
#define NWCH  10            // 10*52 = 520 >= 488
#define NTHREADS (PWN * NJ) // 832
#define XROWN 80            // 76 staged + pad

struct C1mat { float v[P13 * P13]; };  // v[x*13+k] = sqrt(2/13)*Ci[k]*cos((2x+1)k*pi/26)

__global__ __launch_bounds__(NTHREADS, 7) void dct2net_fused(
    const float* __restrict__ xg,
    const float* __restrict__ sigmag,
    float* __restrict__ outg,
    C1mat c1)
{
    __shared__ float xrow[2][XROWN];    // double-buffered staged input row
    __shared__ float red[NJ][PWN];      // pnz cross-wave reduction
    __shared__ float red2[NJ][PWN];     // synthesis partials
    __shared__ float Hrow[NJ][PWN];     // retired vertical-fold row (per kj)
    __shared__ float wring[P13][PWN];   // per-patch-row weights, ring by ph%13
    __shared__ float Hwrow[PWN];        // wave-0 scratch for divisor

    const int tid  = threadIdx.x;
    const int lane = tid & 63;                                   // patch column
    const int ju   = __builtin_amdgcn_readfirstlane(tid >> 6);   // kj, forced scalar
    const int n    = blockIdx.z;
    const int ows  = blockIdx.x * WC;
    const int ohs  = blockIdx.y * SEGH;
    const int ohe  = (ohs + SEGH < OUTW) ? (ohs + SEGH) : OUTW;

    const float inv3s = 1.0f / (3.0f * sigmag[0]);
    const float* xin  = xg + (size_t)n * IMGW * IMGW;

    float Rv[P13], Hreg[P13], pre = 0.0f;
#pragma unroll
    for (int k = 0; k < P13; ++k) { Rv[k] = 0.0f; Hreg[k] = 0.0f; }

    const bool stager = (tid < PWN + P13 - 1);   // 76 loader threads
    int colc = ows + tid; colc = (colc < IMGW) ? colc : (IMGW - 1);
    if (stager) pre = xin[(size_t)ohs * IMGW + colc];

    int ph13 = ohs % P13;        // = ph % 13 during the patch phase
    const int rend = ohe + 23;

    for (int r = ohs; r <= rend; ++r) {
        if (stager) xrow[r & 1][tid] = pre;
        __syncthreads();                                   // B1: publish row r
        {   // prefetch row r+1 (latency hidden under the compute body)
            int pr = r + 1; pr = (pr < IMGW) ? pr : (IMGW - 1);
            if (stager) pre = xin[(size_t)pr * IMGW + colc];
        }
        // --- horizontal DCT for row r -> register shift ring (Rv[x] = row r-12+x)
        {
            float acc = 0.0f;
#pragma unroll
            for (int y = 0; y < P13; ++y) acc += c1.v[y * P13 + ju] * xrow[r & 1][lane + y];
#pragma unroll
            for (int k = 0; k < P13 - 1; ++k) Rv[k] = Rv[k + 1];
            Rv[P13 - 1] = acc;
        }
        if (r >= ohs + 12) {
            // --- vertical DCT + shrinkage (patch row ph = r-12)
            float nzt[P13];
            float pnz = 0.0f;
#pragma unroll
            for (int i = 0; i < P13; ++i) {
                float t = 0.0f;
#pragma unroll
                for (int xk = 0; xk < P13; ++xk) t += c1.v[xk * P13 + i] * Rv[xk];
                float u  = t * inv3s;
                float au = fabsf(u);
                float us = (au < 1.3f) ? u : 0.0f;
                float y2 = us * us, y4 = y2 * y2, y8 = y4 * y4;
                float y16 = y8 * y8, y32 = y16 * y16, y64 = y32 * y32;
                float nz = (au < 1.3f) ? (y64 * __builtin_amdgcn_rcpf(y64 + 1.0f)) : 1.0f;
                pnz += nz;
                nzt[i] = t * nz;
            }
            // --- patch weight w: reduce pnz across the 13 kj-waves
            red[ju][lane] = pnz;
            __syncthreads();                               // B2
            float snz = 0.0f;
#pragma unroll
            for (int jj = 0; jj < NJ; ++jj) snz += red[jj][lane];
            const float w = __builtin_amdgcn_rcpf(1.0f + snz);
            if (ju == NJ - 1) wring[ph13][lane] = w;
#pragma unroll
            for (int i = 0; i < P13; ++i) nzt[i] *= w;
            // --- inverse vertical DCT (even/odd symmetry), accumulate register ring
#pragma unroll
            for (int dx = 0; dx < 6; ++dx) {
                float E = 0.0f, O = 0.0f;
#pragma unroll
                for (int i = 0; i < P13; i += 2) E += c1.v[dx * P13 + i] * nzt[i];
#pragma unroll
                for (int i = 1; i < P13; i += 2) O += c1.v[dx * P13 + i] * nzt[i];
                Hreg[dx]      += E + O;
                Hreg[12 - dx] += E - O;
            }
            {   // center row: c1[6][i] = 0 for odd i
                float z6 = 0.0f;
#pragma unroll
                for (int i = 0; i < P13; i += 2) z6 += c1.v[6 * P13 + i] * nzt[i];
                Hreg[6] += z6;
            }
            // --- retire output row a = ph-12 (patches a..a+12 complete)
            const int a = r - 24;
            const bool doflush = (a >= ohs);               // uniform
            if (doflush) Hrow[ju][lane] = Hreg[0];
#pragma unroll
            for (int k = 0; k < P13 - 1; ++k) Hreg[k] = Hreg[k + 1];
            Hreg[P13 - 1] = 0.0f;
            if (doflush) {
                __syncthreads();                           // B3: publish Hrow
                float part = 0.0f;
#pragma unroll
                for (int dy = 0; dy < P13; ++dy) {
                    int lc = lane + 12 - dy; lc = (lc < PWN) ? lc : (PWN - 1);
                    part += c1.v[dy * P13 + ju] * Hrow[ju][lc];
                }
                red2[ju][lane] = part;
                __syncthreads();                           // B4: publish partials
                if (ju == 0) {
                    float num = 0.0f;
#pragma unroll
                    for (int jj = 0; jj < NJ; ++jj) num += red2[jj][lane];
                    // divisor: vertical box-sum of w from ring, then horizontal
                    int s0 = ph13 + 1; if (s0 >= P13) s0 -= P13;   // = a % 13
                    float hw = 0.0f;
#pragma unroll
                    for (int dx = 0; dx < P13; ++dx) {
                        int s = s0 + dx; if (s >= P13) s -= P13;
                        hw += wring[s][lane];
                    }
                    Hwrow[lane] = hw;                      // same-wave DS ops are in-order
                    float den = 0.0f;
#pragma unroll
                    for (int dy = 0; dy < P13; ++dy) {
                        int lc = lane + 12 - dy; lc = (lc < PWN) ? lc : (PWN - 1);
                        den += Hwrow[lc];
                    }
                    int ow = ows + lane;
                    if (lane < WC && ow < OUTW)
                        outg[((size_t)n * OUTW + a) * OUTW + ow] = num * __builtin_amdgcn_rcpf(den);
                }
            }
            ph13 = (ph13 + 1 == P13) ? 0 : ph13 + 1;
        }
    }
}

extern "C" void kernel_launch(void* const* d_in, const int* in_sizes, int n_in,
                              void* d_out, int out_size, void* d_ws, size_t ws_size,
                              hipStream_t stream)
{
    const float* x     = (const float*)d_in[0];
    const float* sigma = (const float*)d_in[1];
    float* out = (float*)d_out;

    C1mat c1;
    const double PI = 3.14159265358979323846;
    for (int xx = 0; xx < 13; ++xx)
        for (int k = 0; k < 13; ++k) {
            double Ci = (k == 0) ? (1.0 / sqrt(2.0)) : 1.0;
            c1.v[xx * 13 + k] =
                (float)(sqrt(2.0 / 13.0) * Ci * cos((2 * xx + 1) * k * PI / 26.0));
        }

    dim3 grid(NWCH, NSEG, 2);   // 10 col-chunks x 25 row-segments x 2 images = 500 blocks
    dim3 block(NTHREADS);       // 832 = 64 patch-cols x 13 kj-waves
    dct2net_fused<<<grid, block, 0, stream>>>(x, sigma, out, c1);
}